// Round 12
// baseline (839.498 us; speedup 1.0000x reference)
//
#include <hip/hip_runtime.h>
#include <math.h>

#define N_NODES 50000
#define N_EDGES 800000
#define HID 64
#define HEADS 4
#define HC 256
#define NEG_SLOPE 0.2f
#define LN_EPS 1e-5f

typedef __attribute__((ext_vector_type(8))) short bf16x8;
typedef __attribute__((ext_vector_type(8))) unsigned short u16x8;
typedef __attribute__((ext_vector_type(4))) float f32x4;

__device__ __forceinline__ float bf2f(unsigned short u) {
    return __uint_as_float(((unsigned int)u) << 16);
}
__device__ __forceinline__ unsigned short f2bf(float f) {
    unsigned int u = __float_as_uint(f);
    u = (u + 0x7fffu + ((u >> 16) & 1u)) >> 16;   // RNE
    return (unsigned short)u;
}
__device__ __forceinline__ float fast_tanh(float v) {
    const float c = fminf(fmaxf(v, -15.f), 15.f);
    const float e = __expf(2.f * c);
    return 1.f - 2.f / (e + 1.f);
}

// ---------------- K1: xl -> TRANSPOSED-TILED bf16; xr -> plain bf16 --------
// xl_t[node][pos], pos = (c&15)*16 + (c>>4); xr_bf[node][c] plain.
__global__ __launch_bounds__(256) void k_node_transform(
    const float* __restrict__ x,
    const float* __restrict__ W_l, const float* __restrict__ b_l,
    const float* __restrict__ W_r, const float* __restrict__ b_r,
    unsigned short* __restrict__ xl_t, unsigned short* __restrict__ xr_bf)
{
    __shared__ float xs[8][64];
    __shared__ unsigned short tl[8][256];
    const int n0 = blockIdx.x * 8;
    const int t = threadIdx.x;
    for (int i = t; i < 8 * 64; i += 256) xs[i >> 6][i & 63] = x[n0 * 64 + i];
    __syncthreads();

    float accl[8], accr[8];
    const float bl = b_l[t], br = b_r[t];
#pragma unroll
    for (int n = 0; n < 8; n++) { accl[n] = bl; accr[n] = br; }
    for (int k = 0; k < 64; k++) {
        const float wl = W_l[k * 256 + t];
        const float wr = W_r[k * 256 + t];
#pragma unroll
        for (int n = 0; n < 8; n++) {
            accl[n] = fmaf(xs[n][k], wl, accl[n]);
            accr[n] = fmaf(xs[n][k], wr, accr[n]);
        }
    }
    const int pos = (t & 15) * 16 + (t >> 4);   // transposed-tiled position of channel t
#pragma unroll
    for (int n = 0; n < 8; n++) {
        tl[n][pos] = f2bf(accl[n]);
        xr_bf[(n0 + n) * 256 + t] = f2bf(accr[n]);   // plain, coalesced
    }
    __syncthreads();
    // coalesced write-out of tiled xl: thread t -> node t>>5, 8 ushorts at (t&31)*8
    const int n = t >> 5, q = t & 31;
    ushort4 v0 = *(const ushort4*)&tl[n][q * 8];
    ushort4 v1 = *(const ushort4*)&tl[n][q * 8 + 4];
    *(ushort4*)(xl_t + (size_t)(n0 + n) * 256 + q * 8)     = v0;
    *(ushort4*)(xl_t + (size_t)(n0 + n) * 256 + q * 8 + 4) = v1;
}

// ---------------- K1b: prep W_e B-frags (bf16) ------------------------------
__global__ __launch_bounds__(256) void k_prep(
    const float* __restrict__ W_e, unsigned short* __restrict__ wfrag)
{
    const int t = threadIdx.x;
#pragma unroll
    for (int s = 0; s < 4; s++) {
        const int slot = t * 4 + s;            // 1024 slots = 16 nt x 64 lanes
        const int nt = slot >> 6, ls = slot & 63;
        const int col = nt * 16 + (ls & 15);
        const int kb = (ls >> 4) * 8;
#pragma unroll
        for (int j = 0; j < 8; j++)
            wfrag[slot * 8 + j] = f2bf(W_e[(kb + j) * 256 + col]);
    }
}

// ---------------- K2: histogram of dst ------------------------------------
__global__ __launch_bounds__(256) void k_hist(const int* __restrict__ ei, int* __restrict__ count)
{
    const int e = blockIdx.x * 256 + threadIdx.x;
    if (e < N_EDGES) atomicAdd(&count[ei[N_EDGES + e]], 1);
}

// ---------------- K3: exclusive scan (single block) ------------------------
__global__ __launch_bounds__(1024) void k_scan(const int* __restrict__ count, int* __restrict__ off)
{
    __shared__ int wsum[16];
    __shared__ int s_carry;
    const int t = threadIdx.x, lane = t & 63, wv = t >> 6;
    if (t == 0) s_carry = 0;
    __syncthreads();
    for (int base = 0; base < N_NODES; base += 8192) {
        const int idx0 = base + t * 8;
        int v[8];
#pragma unroll
        for (int j = 0; j < 8; j++) { int i = idx0 + j; v[j] = (i < N_NODES) ? count[i] : 0; }
#pragma unroll
        for (int j = 1; j < 8; j++) v[j] += v[j - 1];
        const int tot = v[7];
        int sc = tot;
#pragma unroll
        for (int s = 1; s < 64; s <<= 1) { int o = __shfl_up(sc, s, 64); if (lane >= s) sc += o; }
        if (lane == 63) wsum[wv] = sc;
        __syncthreads();
        const int carry = s_carry;
        int woff = 0;
        for (int u = 0; u < wv; u++) woff += wsum[u];
        const int ebase = carry + woff + (sc - tot);
#pragma unroll
        for (int j = 0; j < 8; j++) {
            int i = idx0 + j;
            if (i < N_NODES) off[i] = ebase + (j ? v[j - 1] : 0);
        }
        __syncthreads();
        if (t == 0) { int tt = 0; for (int u = 0; u < 16; u++) tt += wsum[u]; s_carry = carry + tt; }
        __syncthreads();
    }
    if (threadIdx.x == 0) off[N_NODES] = s_carry;
}

// ---------------- K4: scatter src + PERMUTED bf16 edge_attr into CSR -------
__global__ __launch_bounds__(256) void k_scatter(
    const int* __restrict__ ei, const int* __restrict__ off, int* __restrict__ cursor,
    const float* __restrict__ edge_attr,
    int* __restrict__ csr_src, unsigned short* __restrict__ ea_csr)
{
    const int e = blockIdx.x * 256 + threadIdx.x;
    if (e < N_EDGES) {
        const int s = ei[e];
        const int d = ei[N_EDGES + e];
        const int pos = off[d] + atomicAdd(&cursor[d], 1);
        csr_src[pos] = s;
        const float4* src4 = (const float4*)(edge_attr + (size_t)e * 32);
        ushort4* dst4 = (ushort4*)(ea_csr + (size_t)pos * 32);
#pragma unroll
        for (int i = 0; i < 8; i++) {
            const float4 v = src4[i];
            ushort4 u;
            u.x = f2bf(v.x); u.y = f2bf(v.y); u.z = f2bf(v.z); u.w = f2bf(v.w);
            dst4[i] = u;
        }
    }
}

// ---------------- K5: FUSED all-register D-layout edge pipeline ------------
// 4 waves/block, wave = one node. Lane (arow=l&15, koct=l>>4) owns, for its
// 4 edges (D rows koct*4+r), channels {nt*16+arow}. att/xr read from LDS
// (channel-major, conflict-free) to cut persistent VGPRs; per-head logit
// phase keeps transients at 4 regs.
__global__ __launch_bounds__(256) void k_fused(
    const int* __restrict__ off, const int* __restrict__ csr_src,
    const unsigned short* __restrict__ ea_csr,
    const unsigned short* __restrict__ wfrag, const float* __restrict__ att,
    const unsigned short* __restrict__ xl_t, const unsigned short* __restrict__ xr_bf,
    const float* __restrict__ x, const float* __restrict__ bias_gat,
    const float* __restrict__ W1, const float* __restrict__ b1,
    const float* __restrict__ gamma, const float* __restrict__ beta,
    const float* __restrict__ W2, const float* __restrict__ b2,
    float* __restrict__ out)
{
    __shared__ unsigned short bfrag_s[16][64][8];   // 16 KB W_e B-frags
    __shared__ float xr_sf[4][256];                 // per-wave xr row, channel-major f32
    __shared__ float att_sf[256];                   // att, channel-major f32
    __shared__ float zs[4][256];
    __shared__ float xs[4][64];
    __shared__ float part[4][4][64];
    __shared__ float redS[4][4], redQ[4][4];

    const int n0 = blockIdx.x * 4;
    const int t = threadIdx.x;
    const int lane = t & 63, wv = t >> 6;
    const int node = n0 + wv;
    const int arow = lane & 15, koct = lane >> 4;

    for (int i = t; i < 4 * 64; i += 256) xs[i >> 6][i & 63] = x[n0 * 64 + i];
    for (int i = t; i < 1024; i += 256)
        *(u16x8*)&bfrag_s[i >> 6][i & 63][0] = *(const u16x8*)(wfrag + i * 8);
    att_sf[t] = att[t];
    {   // stage xr row (plain bf16 -> f32), linear read + linear write
        const ushort4 v = *(const ushort4*)(xr_bf + (size_t)node * 256 + lane * 4);
        xr_sf[wv][lane * 4 + 0] = bf2f(v.x);
        xr_sf[wv][lane * 4 + 1] = bf2f(v.y);
        xr_sf[wv][lane * 4 + 2] = bf2f(v.z);
        xr_sf[wv][lane * 4 + 3] = bf2f(v.w);
    }
    __syncthreads();

    const int mylo = off[node], myhi = off[node + 1];
    float g[16];
#pragma unroll
    for (int i = 0; i < 16; i++) g[i] = 0.f;
    float dsum[4] = {0.f, 0.f, 0.f, 0.f};

    for (int p0 = mylo; p0 < myhi; p0 += 16) {
        const int pa = min(p0 + arow, myhi - 1);
        const int sv = csr_src[pa];
        const bf16x8 af = *(const bf16x8*)(ea_csr + (size_t)pa * 32 + koct * 8);
        int src[4];
#pragma unroll
        for (int r = 0; r < 4; r++) src[r] = __shfl(sv, koct * 4 + r, 64);
        u16x8 xlo[4], xhi[4];
#pragma unroll
        for (int r = 0; r < 4; r++) {
            const unsigned short* bp = xl_t + (size_t)src[r] * 256 + arow * 16;
            xlo[r] = *(const u16x8*)bp;
            xhi[r] = *(const u16x8*)(bp + 8);
        }
#pragma unroll
        for (int h = 0; h < 4; h++) {
            float s4[4] = {0.f, 0.f, 0.f, 0.f};
#pragma unroll
            for (int q = 0; q < 4; q++) {
                const int nt = h * 4 + q;
                const bf16x8 bfr = *(const bf16x8*)&bfrag_s[nt][lane][0];
                f32x4 dacc = {0.f, 0.f, 0.f, 0.f};
                dacc = __builtin_amdgcn_mfma_f32_16x16x32_bf16(af, bfr, dacc, 0, 0, 0);
                const float xrv = xr_sf[wv][nt * 16 + arow];
                const float atv = att_sf[nt * 16 + arow];
#pragma unroll
                for (int r = 0; r < 4; r++) {
                    const float xv = bf2f((unsigned short)(nt < 8 ? xlo[r][nt & 7] : xhi[r][nt & 7]));
                    const float mm = dacc[r] + xv + xrv;
                    const float lk = fmaf(NEG_SLOPE, fminf(mm, 0.f), fmaxf(mm, 0.f));
                    s4[r] = fmaf(atv, lk, s4[r]);
                }
            }
#pragma unroll
            for (int r = 0; r < 4; r++) {
                float v = s4[r];
                v += __shfl_xor(v, 1, 64);
                v += __shfl_xor(v, 2, 64);
                v += __shfl_xor(v, 4, 64);
                v += __shfl_xor(v, 8, 64);
                s4[r] = v;
            }
            float w4[4];
#pragma unroll
            for (int r = 0; r < 4; r++)
                w4[r] = (p0 + koct * 4 + r < myhi) ? __expf(fminf(s4[r], 60.f)) : 0.f;
            dsum[h] += (w4[0] + w4[1]) + (w4[2] + w4[3]);
#pragma unroll
            for (int q = 0; q < 4; q++) {
                const int nt = h * 4 + q;
                float acc = g[nt];
#pragma unroll
                for (int r = 0; r < 4; r++) {
                    const float xv = bf2f((unsigned short)(nt < 8 ? xlo[r][nt & 7] : xhi[r][nt & 7]));
                    acc = fmaf(w4[r], xv, acc);
                }
                g[nt] = acc;
            }
        }
    }
    // cross-koct reduction
#pragma unroll
    for (int i = 0; i < 16; i++) {
        float v = g[i];
        v += __shfl_xor(v, 16, 64);
        v += __shfl_xor(v, 32, 64);
        g[i] = v;
    }
#pragma unroll
    for (int h = 0; h < 4; h++) {
        float v = dsum[h];
        v += __shfl_xor(v, 16, 64);
        v += __shfl_xor(v, 32, 64);
        dsum[h] = v;
    }
    float inv[4];
#pragma unroll
    for (int h = 0; h < 4; h++) inv[h] = 1.f / (dsum[h] + 1e-16f);
#pragma unroll
    for (int nt = 0; nt < 16; nt++) g[nt] *= inv[nt >> 2];
    if (koct == 0) {
#pragma unroll
        for (int nt = 0; nt < 16; nt++) zs[wv][nt * 16 + arow] = g[nt];
    }
    __syncthreads();

    // xl1 = tanh(x@W1+b1), channel t, 4 nodes
    float a1[4];
    const float b1v = b1[t];
#pragma unroll
    for (int n = 0; n < 4; n++) a1[n] = b1v;
    for (int k = 0; k < 64; k++) {
        const float w1v = W1[k * 256 + t];
#pragma unroll
        for (int n = 0; n < 4; n++) a1[n] = fmaf(xs[n][k], w1v, a1[n]);
    }

    const float bg = bias_gat[t];
    float z[4];
#pragma unroll
    for (int n = 0; n < 4; n++) z[n] = fast_tanh(a1[n]) + zs[n][t] + bg;

    // LayerNorm over 256 channels per node
    const float gm = gamma[t], bt = beta[t];
#pragma unroll
    for (int n = 0; n < 4; n++) {
        float s = z[n], q = z[n] * z[n];
#pragma unroll
        for (int m = 1; m < 64; m <<= 1) { s += __shfl_xor(s, m, 64); q += __shfl_xor(q, m, 64); }
        if (lane == 0) { redS[n][wv] = s; redQ[n][wv] = q; }
    }
    __syncthreads();
#pragma unroll
    for (int n = 0; n < 4; n++) {
        const float s = redS[n][0] + redS[n][1] + redS[n][2] + redS[n][3];
        const float q = redQ[n][0] + redQ[n][1] + redQ[n][2] + redQ[n][3];
        const float mu = s * (1.f / 256.f);
        const float var = q * (1.f / 256.f) - mu * mu;
        const float ivn = rsqrtf(var + LN_EPS);
        zs[n][t] = (z[n] - mu) * ivn * gm + bt;
    }
    __syncthreads();

    // out = tanh(z@W2 + b2): thread t -> output col j=t&63, K-chunk q=t>>6
    const int j = t & 63, q = t >> 6;
    float p[4] = {0.f, 0.f, 0.f, 0.f};
    for (int c0 = 0; c0 < 64; c0++) {
        const int c = q * 64 + c0;
        const float w2v = W2[c * 64 + j];
#pragma unroll
        for (int n = 0; n < 4; n++) p[n] = fmaf(zs[n][c], w2v, p[n]);
    }
#pragma unroll
    for (int n = 0; n < 4; n++) part[n][q][j] = p[n];
    __syncthreads();
    {
        const int n = t >> 6, jj = t & 63;
        const float s = part[n][0][jj] + part[n][1][jj] + part[n][2][jj] + part[n][3][jj];
        out[(n0 + n) * 64 + jj] = fast_tanh(s + b2[jj]);
    }
}

// ---------------- launcher --------------------------------------------------
extern "C" void kernel_launch(void* const* d_in, const int* in_sizes, int n_in,
                              void* d_out, int out_size, void* d_ws, size_t ws_size,
                              hipStream_t stream)
{
    const float* x         = (const float*)d_in[0];
    const int*   ei        = (const int*)d_in[1];
    const float* edge_attr = (const float*)d_in[2];
    const float* W_l       = (const float*)d_in[3];
    const float* b_l       = (const float*)d_in[4];
    const float* W_r       = (const float*)d_in[5];
    const float* b_r       = (const float*)d_in[6];
    const float* W_e       = (const float*)d_in[7];
    const float* att       = (const float*)d_in[8];
    const float* bias_gat  = (const float*)d_in[9];
    const float* W1        = (const float*)d_in[10];
    const float* b1        = (const float*)d_in[11];
    const float* gamma     = (const float*)d_in[12];
    const float* beta      = (const float*)d_in[13];
    const float* W2        = (const float*)d_in[14];
    const float* b2        = (const float*)d_in[15];
    float* out = (float*)d_out;

    char* ws = (char*)d_ws;
    unsigned short* xl_t   = (unsigned short*)ws;  ws += (size_t)N_NODES * HC * 2;   // 25.6 MB
    unsigned short* xr_bf  = (unsigned short*)ws;  ws += (size_t)N_NODES * HC * 2;   // 25.6 MB
    unsigned short* ea_csr = (unsigned short*)ws;  ws += (size_t)N_EDGES * 32 * 2;   // 51.2 MB
    int* csr_src           = (int*)ws;             ws += (size_t)N_EDGES * 4;
    int* count             = (int*)ws;             ws += (size_t)N_NODES * 4;
    int* cursor            = (int*)ws;             ws += (size_t)N_NODES * 4;
    int* off               = (int*)ws;             ws += (size_t)(N_NODES + 1) * 4;
    unsigned short* wfrag  = (unsigned short*)ws;  ws += 16 * 64 * 8 * 2;            // 16 KB

    // zero count + cursor (contiguous)
    hipMemsetAsync(count, 0, 2 * (size_t)N_NODES * sizeof(int), stream);

    k_node_transform<<<N_NODES / 8, 256, 0, stream>>>(x, W_l, b_l, W_r, b_r, xl_t, xr_bf);
    k_prep<<<1, 256, 0, stream>>>(W_e, wfrag);
    k_hist<<<(N_EDGES + 255) / 256, 256, 0, stream>>>(ei, count);
    k_scan<<<1, 1024, 0, stream>>>(count, off);
    k_scatter<<<(N_EDGES + 255) / 256, 256, 0, stream>>>(ei, off, cursor, edge_attr,
                                                         csr_src, ea_csr);
    k_fused<<<N_NODES / 4, 256, 0, stream>>>(off, csr_src, ea_csr, wfrag, att,
                                             xl_t, xr_bf, x, bias_gat,
                                             W1, b1, gamma, beta, W2, b2, out);
}